// Round 14
// baseline (210.811 us; speedup 1.0000x reference)
//
#include <hip/hip_runtime.h>
#include <math.h>
#include <stdint.h>

// Problem constants
#define NB 4
#define NC 128
#define NP 4096
#define KNN 10

// ---------------- ws layout (float-slot offsets) ----------------
// Xcat (bf16 u16) : [B][N][512]   @ 0         (4194304 float-slots = 16MB)
// UV   (f32)      : [B][N][512]   @ 4194304
// Mbuf (f32)      : [B][N][256]   @ 12582912  (Y3 aliases, [B][N][128])
// idx  (i32)      : [B][N][10]    @ 16777216
// W1cat (bf16)    : [256][128]    @ 16941056
// W2cat (bf16)    : [512][128]    @ 16957440
// W3b  (bf16)     : [128][512]    @ 16990208
// stats (f32)     : [8192]        @ 17022976
// KNN scratch aliases UV region (all KNN kernels run before stage-1 GEMM):
//   candd: [16384][80]    @ UV+0
//   tq   : [16384]        @ UV+1310720
//   pts4 : float4[16384]  @ UV+1327104  (x,y,z,|p|^2 — single source of truth)

__device__ __forceinline__ uint16_t f2bf(float f) {
  uint32_t u = __float_as_uint(f);
  u += 0x7fffu + ((u >> 16) & 1u);      // RNE
  return (uint16_t)(u >> 16);
}

__device__ __forceinline__ void async16(const void* g, void* l) {
  __builtin_amdgcn_global_load_lds(
      (const __attribute__((address_space(1))) unsigned int*)g,
      (__attribute__((address_space(3))) unsigned int*)l,
      16, 0, 0);
}

// float -> order-preserving uint32 (all finite values)
__device__ __forceinline__ uint32_t fsort(float f) {
  uint32_t u = __float_as_uint(f);
  return (u & 0x80000000u) ? ~u : (u | 0x80000000u);
}
__device__ __forceinline__ float funsort(uint32_t k) {
  uint32_t u = (k & 0x80000000u) ? (k & 0x7fffffffu) : ~k;
  return __uint_as_float(u);
}

typedef __bf16 bf16x8 __attribute__((ext_vector_type(8)));
typedef float f32x4 __attribute__((ext_vector_type(4)));

// prep: weight precompute + stats zero + pts4 pack (x,y,z,|p|^2)
__global__ void k_prep(const float* __restrict__ W1, const float* __restrict__ W2,
                       const float* __restrict__ W3, const float* __restrict__ coords,
                       uint16_t* __restrict__ W1cat, uint16_t* __restrict__ W2cat,
                       uint16_t* __restrict__ W3b,
                       float* __restrict__ stats, float4* __restrict__ pts4) {
  int t = blockIdx.x * 256 + threadIdx.x;
  if (t < 32768) {
    int o = t >> 7, c = t & 127;
    float v;
    if (o < 128) v = W1[o * 256 + c] - W1[o * 256 + 128 + c];     // A1 = W1a - W1b
    else         v = W1[(o - 128) * 256 + 128 + c];               // B1 = W1b
    W1cat[t] = f2bf(v);
  } else if (t < 98304) {
    int t2 = t - 32768;
    int o = t2 >> 7, c = t2 & 127;
    float v;
    if (o < 256) v = W2[o * 256 + c] - W2[o * 256 + 128 + c];     // A2
    else         v = W2[(o - 256) * 256 + 128 + c];               // B2
    W2cat[t2] = f2bf(v);
  } else if (t < 163840) {
    int t2 = t - 98304;
    W3b[t2] = f2bf(W3[t2]);
  } else if (t < 163840 + 8192) {
    stats[t - 163840] = 0.f;
  } else if (t < 163840 + 8192 + 16384) {
    int t2 = t - 163840 - 8192;
    int b = t2 >> 12, n = t2 & 4095;
    const float* cb = coords + b * 12288;
    float x = cb[n], y = cb[4096 + n], z = cb[8192 + n];
    float w = fmaf(x, x, fmaf(y, y, z * z));
    pts4[t2] = make_float4(x, y, z, w);
  }
}

// features [B][128][4096] (f32) -> Xcat[b][n][0:128] (bf16)
__global__ void k_trans_feat(const float* __restrict__ feat, uint16_t* __restrict__ Xcat) {
  __shared__ float tile[32][33];
  int bid = blockIdx.x;           // 2048
  int b = bid >> 9;
  int r = bid & 511;
  int n0 = (r >> 2) << 5;
  int c0 = (r & 3) << 5;
  int tx = threadIdx.x & 31, ty = threadIdx.x >> 5;   // 256 threads
#pragma unroll
  for (int i = 0; i < 4; i++) {
    int c = c0 + ty + i * 8;
    tile[ty + i * 8][tx] = feat[(b * 128 + c) * 4096 + n0 + tx];
  }
  __syncthreads();
#pragma unroll
  for (int i = 0; i < 4; i++) {
    int n = n0 + ty + i * 8;
    Xcat[((b * 4096 + n) * 512) + c0 + tx] = f2bf(tile[tx][ty + i * 8]);
  }
}

// ---------------- KNN: exact subsampled-threshold scheme ----------------
// d = (q.w + p.w) - 2 q.p with explicit fmaf, operands from pts4 everywhere:
// thr and the cf exact-recompute are bit-identical by construction.
// Phase A: per-chunk sorted top-10 over SUBSET = first 1024 points.
__global__ void k_knn_thr(const float4* __restrict__ pts4, float* __restrict__ candd) {
  int L = blockIdx.x;             // 512 = b(4) x qb(16) x ch(8)
  int ch = L & 7;
  int qb = (L >> 3) & 15;
  int b = L >> 7;
  int m0 = ch << 7;               // subset points ch*128 .. +127  (all < 1024)
  const float4* pb = pts4 + b * 4096;
  int t = threadIdx.x;
  int q = (qb << 8) + t;
  float4 qp = pb[q];
  float d10[10];
#pragma unroll
  for (int i = 0; i < 10; i++) d10[i] = 1e30f;
#pragma unroll 2
  for (int mm = 0; mm < 128; mm++) {
    int m = m0 + mm;
    float4 p = pb[m];                     // wave-uniform -> broadcast
    float dot = fmaf(qp.x, p.x, fmaf(qp.y, p.y, qp.z * p.z));
    float s = qp.w + p.w;
    float d = fmaf(-2.f, dot, s);
    d = (m == q) ? 1e30f : d;             // self-exclusion
    if (d < d10[9]) {
      float carry = d;
#pragma unroll
      for (int i = 0; i < 10; i++) {
        float lo = fminf(d10[i], carry);
        carry = fmaxf(d10[i], carry);
        d10[i] = lo;
      }
    }
  }
  int row = b * 4096 + q;
#pragma unroll
  for (int i = 0; i < 10; i++) candd[row * 80 + ch * 10 + i] = d10[i];
}

// Phase B: wave-per-query exact 10th-smallest of the 80 subset candidates.
__global__ void k_knn_merge(const float* __restrict__ candd, float* __restrict__ tq) {
  int gw = blockIdx.x * 4 + (threadIdx.x >> 6);   // 4096 blocks -> 16384 waves
  int l = threadIdx.x & 63;
  const float* cp = candd + (size_t)gw * 80;
  uint32_t k0 = fsort(cp[l]);
  uint32_t k1 = (l < 16) ? fsort(cp[64 + l]) : 0xFFFFFFFFu;
  uint32_t g = 0;
#pragma unroll
  for (int it = 0; it < 10; it++) {
    uint32_t m = k0 < k1 ? k0 : k1;
#pragma unroll
    for (int s = 1; s < 64; s <<= 1) {
      uint32_t o = __shfl_xor(m, s);
      m = o < m ? o : m;
    }
    g = m;
    if (it < 9) {
      if (k0 == m) k0 = 0xFFFFFFFFu;
      else if (k1 == m) k1 = 0xFFFFFFFFu;
    }
  }
  if (l == 0) tq[gw] = funsort(g);
}

// Phase C+D fused: WHOLE-BATCH LDS residency. Block = (b, 32-query group);
// stage all 4096 points (64 KB) once with ONE barrier, then each thread
// scans its 512-point range from LDS with the cheap 3-fma filter — no
// barriers, no global loads in the loop. Lane layout ql=t&31, sub=t>>5:
// lanes 0-31 / 32-63 of a wave read the SAME sp address -> broadcast,
// zero bank conflicts, NO padding (sp stays linear 64 KB).
// Candidates = indices only; selection recomputes EXACT d from the LDS
// copy (bit-identical data + identical fmaf chain vs k_knn_thr).
// LDS: 64 KB sp + 14 KB candi + ccnt = 80.0 KB -> 2 blocks/CU.
#define CFCAP 112
#define DMARGIN 1e-3f
__global__ __launch_bounds__(256) void k_knn_cf(
    const float4* __restrict__ pts4, const float* __restrict__ tq,
    int* __restrict__ idxout) {
  __shared__ float4 sp[4096];               // 64 KB, linear
  __shared__ int candi[32 * CFCAP];         // 14 KB
  __shared__ int ccnt[32];
  int blk = blockIdx.x;           // 512 = b(4) x qg(128)
  int b = blk >> 7;
  int qg = blk & 127;
  int t = threadIdx.x;
  int ql = t & 31;                // query within group
  int sub = t >> 5;               // 0..7 -> point range sub*512..+511
  if (t < 32) ccnt[t] = 0;
  const float4* pb = pts4 + b * 4096;
  // stage whole batch: 16 coalesced float4 loads per thread
#pragma unroll
  for (int c = 0; c < 16; c++) sp[c * 256 + t] = pb[c * 256 + t];
  int q = qg * 32 + ql;
  float4 qp = pb[q];
  float q2x = -2.f * qp.x, q2y = -2.f * qp.y, q2z = -2.f * qp.z;
  float rhs = tq[b * 4096 + q] + DMARGIN - qp.w;
  __syncthreads();                // staging + ccnt init visible
  int base = sub * 512;
#pragma unroll 8
  for (int i = 0; i < 512; i++) {
    float4 p = sp[base + i];      // broadcast read (same addr per 32 lanes)
    float tt = fmaf(q2x, p.x, fmaf(q2y, p.y, fmaf(q2z, p.z, p.w)));
    if (tt <= rhs) {
      int pos = atomicAdd(&ccnt[ql], 1);
      if (pos < CFCAP) candi[ql * CFCAP + pos] = base + i;
    }
  }
  __syncthreads();
  // selection: 4 waves; wave w handles queries w*8 .. w*8+7.
  // Recompute EXACT d (bit-identical chain vs thr) from the LDS copy.
  int w = t >> 6;
  int l = t & 63;
  for (int k = 0; k < 8; k++) {
    int ql2 = w * 8 + k;
    int q2 = qg * 32 + ql2;
    float4 qp2 = sp[q2];
    int c = ccnt[ql2]; c = c < CFCAP ? c : CFCAP;
    unsigned long long k0 = ~0ULL, k1 = ~0ULL;
#pragma unroll
    for (int u = 0; u < 2; u++) {
      int j = u * 64 + l;
      if (j < c) {
        int m = candi[ql2 * CFCAP + j];
        float4 p = sp[m];
        float dot = fmaf(qp2.x, p.x, fmaf(qp2.y, p.y, qp2.z * p.z));
        float s = qp2.w + p.w;
        float d = fmaf(-2.f, dot, s);        // EXACT, bit-identical to thr
        d = (m == q2) ? 1e30f : d;           // self-exclusion
        unsigned long long key = (((unsigned long long)fsort(d)) << 32) | (uint32_t)m;
        if (u == 0) k0 = key; else k1 = key;
      }
    }
    uint32_t keep[10];
#pragma unroll
    for (int it = 0; it < 10; it++) {
      unsigned long long m = k0 < k1 ? k0 : k1;
#pragma unroll
      for (int s = 1; s < 64; s <<= 1) {
        unsigned long long o = __shfl_xor(m, s);
        m = o < m ? o : m;
      }
      keep[it] = (uint32_t)(m & 0xffffffffu);
      if (k0 == m) k0 = ~0ULL;
      else if (k1 == m) k1 = ~0ULL;
    }
    if (l == 0) {
      int orow = b * 4096 + q2;
#pragma unroll
      for (int i = 0; i < 10; i++) idxout[orow * 10 + i] = (int)keep[i];
    }
  }
}

// ---------------- bf16 MFMA GEMM ----------------
// Y[p][o] = sum_k X[p][xoff+k] * W[o][k]   (X,W bf16; Y f32)
// BM=128, BN=64, BK=64. 256 threads = 4 waves (2x2). mfma 16x16x32.
__global__ __launch_bounds__(256) void k_gemm_bf(
    const uint16_t* __restrict__ Xb, int ldx, int xoff,
    const uint16_t* __restrict__ Wb, int ldw,
    float* __restrict__ Y, int ldy, int K) {
  __shared__ __align__(16) uint8_t lds[49152];
  const int t = threadIdx.x;
  const int l = t & 63;
  const int wid = t >> 6;
  const int wr = wid & 1, wc = wid >> 1;
  const int p0 = blockIdx.x * 128;
  const int o0 = blockIdx.y * 64;

  const int rA = l >> 3;                         // row within 8-row chunk
  const int cbp = ((l & 7) ^ rA) << 4;           // pre-swizzled byte col (staging)
  const int swl = (l & 7) << 4;                  // read-side swizzle XOR

  f32x4 acc[4][2];
#pragma unroll
  for (int mi = 0; mi < 4; mi++)
#pragma unroll
    for (int ni = 0; ni < 2; ni++) acc[mi][ni] = (f32x4)0.f;

  auto stage = [&](int k0, int buf) {
    const uint16_t* Xs_ = Xb + (size_t)p0 * ldx + xoff + k0;
    const uint16_t* Ws_ = Wb + (size_t)o0 * ldw + k0;
#pragma unroll
    for (int cc = 0; cc < 4; cc++) {
      int c = wid * 4 + cc;                      // A chunk 0..15 -> rows c*8..c*8+8
      const uint8_t* g = (const uint8_t*)(Xs_ + (size_t)(c * 8 + rA) * ldx) + cbp;
      async16(g, &lds[buf * 16384 + c * 1024]);
    }
#pragma unroll
    for (int cc = 0; cc < 2; cc++) {
      int c = wid * 2 + cc;                      // B chunk 0..7
      const uint8_t* g = (const uint8_t*)(Ws_ + (size_t)(c * 8 + rA) * ldw) + cbp;
      async16(g, &lds[32768 + buf * 8192 + c * 1024]);
    }
  };

  auto compute = [&](int buf) {
    const uint8_t* Ab = &lds[buf * 16384];
    const uint8_t* Bb = &lds[32768 + buf * 8192];
#pragma unroll
    for (int ks = 0; ks < 2; ks++) {
      int cb = ks * 64 + ((l >> 4) << 4);
      bf16x8 bfr[2];
#pragma unroll
      for (int ni = 0; ni < 2; ni++) {
        int n = wc * 32 + ni * 16 + (l & 15);
        bfr[ni] = *(const bf16x8*)(Bb + n * 128 + (cb ^ swl));
      }
#pragma unroll
      for (int mi = 0; mi < 4; mi++) {
        int m = wr * 64 + mi * 16 + (l & 15);
        bf16x8 afr = *(const bf16x8*)(Ab + m * 128 + (cb ^ swl));
        acc[mi][0] = __builtin_amdgcn_mfma_f32_16x16x32_bf16(afr, bfr[0], acc[mi][0], 0, 0, 0);
        acc[mi][1] = __builtin_amdgcn_mfma_f32_16x16x32_bf16(afr, bfr[1], acc[mi][1], 0, 0, 0);
      }
    }
  };

  const int nsteps = K >> 6;
  stage(0, 0);
  for (int s = 0; s < nsteps; s++) {
    __syncthreads();                              // drains in-flight loads
    if (s + 1 < nsteps) stage((s + 1) << 6, (s + 1) & 1);
    compute(s & 1);
  }

#pragma unroll
  for (int mi = 0; mi < 4; mi++)
#pragma unroll
    for (int ni = 0; ni < 2; ni++) {
      int col = o0 + wc * 32 + ni * 16 + (l & 15);
      int row0 = p0 + wr * 64 + mi * 16 + (l >> 4) * 4;
#pragma unroll
      for (int j = 0; j < 4; j++)
        Y[(size_t)(row0 + j) * ldy + col] = acc[mi][ni][j];
    }
}

// Gather pass (fp32 UV)
template <int O>
__global__ void k_gather(const float* __restrict__ UV, int ld, int voff,
                         const int* __restrict__ idx,
                         float* __restrict__ M,
                         float* __restrict__ T1, float* __restrict__ T2) {
  int L = blockIdx.x;             // 1024 blocks
  int rx = L & 7;
  int b = rx >> 1;
  int j = ((L >> 3) << 1) + (rx & 1);
  int n0 = j << 4;
  int o = threadIdx.x;
  float a1 = 0.f, a2 = 0.f;
  for (int pi = 0; pi < 16; pi++) {
    int row = b * 4096 + n0 + pi;
    float u = UV[row * ld + o];
    float s1 = 0.f, s2 = 0.f, vmax = -1e30f;
#pragma unroll
    for (int jj = 0; jj < KNN; jj++) {
      int m = idx[row * 10 + jj];
      float v = UV[(b * 4096 + m) * ld + voff + o];
      s1 += v;
      float x = u + v;
      s2 = fmaf(x, x, s2);
      vmax = fmaxf(vmax, v);
    }
    M[row * O + o] = vmax;
    a1 += 10.f * u + s1;
    a2 += s2;
  }
  atomicAdd(&T1[b * O + o], a1);
  atomicAdd(&T2[b * O + o], a2);
}

// x = lrelu((U + maxV - mu) * rsqrt(var+eps)) -> Xcat[:, coff:coff+O] (bf16)
template <int O>
__global__ void k_passB(const float* __restrict__ UV, int ld,
                        const float* __restrict__ M, int coff,
                        const float* __restrict__ T1, const float* __restrict__ T2,
                        uint16_t* __restrict__ Xcat) {
  int t = blockIdx.x * 256 + threadIdx.x;
  int o = t & (O - 1);
  int pn = t / O;
  int b = pn >> 12;
  float mu = T1[b * O + o] * (1.f / 40960.f);
  float e2 = T2[b * O + o] * (1.f / 40960.f);
  float inv = rsqrtf(e2 - mu * mu + 1e-5f);
  float x = (UV[pn * ld + o] + M[pn * O + o] - mu) * inv;
  Xcat[pn * 512 + coff + o] = f2bf(x >= 0.f ? x : 0.2f * x);
}

__global__ void k_stats3(const float* __restrict__ Y3, float* __restrict__ T1, float* __restrict__ T2) {
  int L = blockIdx.x;             // 1024
  int rx = L & 7;
  int b = rx >> 1;
  int j = ((L >> 3) << 1) + (rx & 1);
  int n0 = j << 4;
  int o = threadIdx.x;            // 128
  float a1 = 0.f, a2 = 0.f;
  for (int pi = 0; pi < 16; pi++) {
    float y = Y3[(b * 4096 + n0 + pi) * 128 + o];
    a1 += y;
    a2 = fmaf(y, y, a2);
  }
  atomicAdd(&T1[b * 128 + o], a1);
  atomicAdd(&T2[b * 128 + o], a2);
}

// out[b][o][n] = lrelu((Y3[b][n][o]-mu)*inv)  (transposing write)
__global__ void k_out(const float* __restrict__ Y3, const float* __restrict__ T1,
                      const float* __restrict__ T2, float* __restrict__ out) {
  __shared__ float tile[32][33];
  int bid = blockIdx.x;           // 2048
  int b = bid >> 9;
  int r = bid & 511;
  int n0 = (r >> 2) << 5;
  int o0 = (r & 3) << 5;
  int tx = threadIdx.x & 31, ty = threadIdx.x >> 5;
  int o = o0 + tx;
  float mu = T1[b * 128 + o] * (1.f / 4096.f);
  float e2 = T2[b * 128 + o] * (1.f / 4096.f);
  float inv = rsqrtf(e2 - mu * mu + 1e-5f);
#pragma unroll
  for (int i = 0; i < 4; i++) {
    int n = n0 + ty + i * 8;
    float v = (Y3[(b * 4096 + n) * 128 + o] - mu) * inv;
    tile[ty + i * 8][tx] = v >= 0.f ? v : 0.2f * v;
  }
  __syncthreads();
#pragma unroll
  for (int i = 0; i < 4; i++) {
    int oo = o0 + ty + i * 8;
    out[(b * 128 + oo) * 4096 + n0 + tx] = tile[tx][ty + i * 8];
  }
}

extern "C" void kernel_launch(void* const* d_in, const int* in_sizes, int n_in,
                              void* d_out, int out_size, void* d_ws, size_t ws_size,
                              hipStream_t stream) {
  const float* coords   = (const float*)d_in[0];
  const float* features = (const float*)d_in[1];
  const float* W1       = (const float*)d_in[2];
  const float* W2       = (const float*)d_in[3];
  const float* W3       = (const float*)d_in[4];
  float* out = (float*)d_out;

  float*    ws    = (float*)d_ws;
  uint16_t* Xcat  = (uint16_t*)ws;                 // bf16 [4][4096][512]
  float*    UV    = ws + 4194304;
  float*    Mbuf  = ws + 12582912;
  float*    Y3    = Mbuf;                          // alias (M dead by fuse GEMM)
  int*      idxb  = (int*)(ws + 16777216);
  uint16_t* W1cat = (uint16_t*)(ws + 16941056);
  uint16_t* W2cat = (uint16_t*)(ws + 16957440);
  uint16_t* W3b   = (uint16_t*)(ws + 16990208);
  float*    stats = ws + 17022976;
  // KNN scratch aliases UV region (all KNN kernels complete before stage-1 GEMM)
  float*  candd = UV;
  float*  tq    = UV + 1310720;
  float4* pts4  = (float4*)(UV + 1327104);

  k_prep<<<736, 256, 0, stream>>>(W1, W2, W3, coords, W1cat, W2cat, W3b, stats, pts4);
  k_trans_feat<<<2048, 256, 0, stream>>>(features, Xcat);
  k_knn_thr<<<512, 256, 0, stream>>>(pts4, candd);
  k_knn_merge<<<4096, 256, 0, stream>>>(candd, tq);
  k_knn_cf<<<512, 256, 0, stream>>>(pts4, tq, idxb);

  // stage 1: UV = Xcat[:, 0:128] @ W1cat^T  (O=256)
  k_gemm_bf<<<dim3(128, 4), 256, 0, stream>>>(Xcat, 512, 0, W1cat, 128, UV, 256, 128);
  k_gather<128><<<1024, 128, 0, stream>>>(UV, 256, 128, idxb, Mbuf, stats + 0, stats + 512);
  k_passB<128><<<8192, 256, 0, stream>>>(UV, 256, Mbuf, 128, stats + 0, stats + 512, Xcat);

  // stage 2: UV = Xcat[:, 128:256] @ W2cat^T (O=512)
  k_gemm_bf<<<dim3(128, 8), 256, 0, stream>>>(Xcat, 512, 128, W2cat, 128, UV, 512, 128);
  k_gather<256><<<1024, 256, 0, stream>>>(UV, 512, 256, idxb, Mbuf, stats + 1024, stats + 2048);
  k_passB<256><<<16384, 256, 0, stream>>>(UV, 512, Mbuf, 256, stats + 1024, stats + 2048, Xcat);

  // fuse: Y3 = Xcat[:, 0:512] @ W3b^T (O=128)
  k_gemm_bf<<<dim3(128, 2), 256, 0, stream>>>(Xcat, 512, 0, W3b, 512, Y3, 128, 512);
  k_stats3<<<1024, 128, 0, stream>>>(Y3, stats + 3072, stats + 3584);
  k_out<<<2048, 256, 0, stream>>>(Y3, stats + 3072, stats + 3584, out);
}

// Round 15
// 201.577 us; speedup vs baseline: 1.0458x; 1.0458x over previous
//
#include <hip/hip_runtime.h>
#include <math.h>
#include <stdint.h>

// Problem constants
#define NB 4
#define NC 128
#define NP 4096
#define KNN 10

// ---------------- ws layout (float-slot offsets) ----------------
// Xcat (bf16 u16) : [B][N][512]   @ 0         (4194304 float-slots = 16MB)
// UV   (f32)      : [B][N][512]   @ 4194304
// Mbuf (f32)      : [B][N][256]   @ 12582912  (Y3 aliases, [B][N][128])
// idx  (i32)      : [B][N][10]    @ 16777216
// W1cat (bf16)    : [256][128]    @ 16941056
// W2cat (bf16)    : [512][128]    @ 16957440
// W3b  (bf16)     : [128][512]    @ 16990208
// stats (f32)     : [8192]        @ 17022976
// KNN scratch aliases UV region (all KNN kernels run before stage-1 GEMM):
//   candd: [16384][80]    @ UV+0
//   tq   : [16384]        @ UV+1310720
//   pts4 : float4[16384]  @ UV+1327104  (x,y,z,|p|^2 — single source of truth)

__device__ __forceinline__ uint16_t f2bf(float f) {
  uint32_t u = __float_as_uint(f);
  u += 0x7fffu + ((u >> 16) & 1u);      // RNE
  return (uint16_t)(u >> 16);
}

__device__ __forceinline__ void async16(const void* g, void* l) {
  __builtin_amdgcn_global_load_lds(
      (const __attribute__((address_space(1))) unsigned int*)g,
      (__attribute__((address_space(3))) unsigned int*)l,
      16, 0, 0);
}

// float -> order-preserving uint32 (all finite values)
__device__ __forceinline__ uint32_t fsort(float f) {
  uint32_t u = __float_as_uint(f);
  return (u & 0x80000000u) ? ~u : (u | 0x80000000u);
}
__device__ __forceinline__ float funsort(uint32_t k) {
  uint32_t u = (k & 0x80000000u) ? (k & 0x7fffffffu) : ~k;
  return __uint_as_float(u);
}

typedef __bf16 bf16x8 __attribute__((ext_vector_type(8)));
typedef float f32x4 __attribute__((ext_vector_type(4)));

// prep: weight precompute + stats zero + pts4 pack (x,y,z,|p|^2)
__global__ void k_prep(const float* __restrict__ W1, const float* __restrict__ W2,
                       const float* __restrict__ W3, const float* __restrict__ coords,
                       uint16_t* __restrict__ W1cat, uint16_t* __restrict__ W2cat,
                       uint16_t* __restrict__ W3b,
                       float* __restrict__ stats, float4* __restrict__ pts4) {
  int t = blockIdx.x * 256 + threadIdx.x;
  if (t < 32768) {
    int o = t >> 7, c = t & 127;
    float v;
    if (o < 128) v = W1[o * 256 + c] - W1[o * 256 + 128 + c];     // A1 = W1a - W1b
    else         v = W1[(o - 128) * 256 + 128 + c];               // B1 = W1b
    W1cat[t] = f2bf(v);
  } else if (t < 98304) {
    int t2 = t - 32768;
    int o = t2 >> 7, c = t2 & 127;
    float v;
    if (o < 256) v = W2[o * 256 + c] - W2[o * 256 + 128 + c];     // A2
    else         v = W2[(o - 256) * 256 + 128 + c];               // B2
    W2cat[t2] = f2bf(v);
  } else if (t < 163840) {
    int t2 = t - 98304;
    W3b[t2] = f2bf(W3[t2]);
  } else if (t < 163840 + 8192) {
    stats[t - 163840] = 0.f;
  } else if (t < 163840 + 8192 + 16384) {
    int t2 = t - 163840 - 8192;
    int b = t2 >> 12, n = t2 & 4095;
    const float* cb = coords + b * 12288;
    float x = cb[n], y = cb[4096 + n], z = cb[8192 + n];
    float w = fmaf(x, x, fmaf(y, y, z * z));
    pts4[t2] = make_float4(x, y, z, w);
  }
}

// features [B][128][4096] (f32) -> Xcat[b][n][0:128] (bf16)
__global__ void k_trans_feat(const float* __restrict__ feat, uint16_t* __restrict__ Xcat) {
  __shared__ float tile[32][33];
  int bid = blockIdx.x;           // 2048
  int b = bid >> 9;
  int r = bid & 511;
  int n0 = (r >> 2) << 5;
  int c0 = (r & 3) << 5;
  int tx = threadIdx.x & 31, ty = threadIdx.x >> 5;   // 256 threads
#pragma unroll
  for (int i = 0; i < 4; i++) {
    int c = c0 + ty + i * 8;
    tile[ty + i * 8][tx] = feat[(b * 128 + c) * 4096 + n0 + tx];
  }
  __syncthreads();
#pragma unroll
  for (int i = 0; i < 4; i++) {
    int n = n0 + ty + i * 8;
    Xcat[((b * 4096 + n) * 512) + c0 + tx] = f2bf(tile[tx][ty + i * 8]);
  }
}

// ---------------- KNN: exact subsampled-threshold scheme ----------------
// d = (q.w + p.w) - 2 q.p with explicit fmaf, operands from pts4 everywhere:
// thr and the cf exact-recompute are bit-identical by construction.
// Phase A: per-chunk sorted top-10 over SUBSET = first 1024 points.
__global__ void k_knn_thr(const float4* __restrict__ pts4, float* __restrict__ candd) {
  int L = blockIdx.x;             // 512 = b(4) x qb(16) x ch(8)
  int ch = L & 7;
  int qb = (L >> 3) & 15;
  int b = L >> 7;
  int m0 = ch << 7;               // subset points ch*128 .. +127  (all < 1024)
  const float4* pb = pts4 + b * 4096;
  int t = threadIdx.x;
  int q = (qb << 8) + t;
  float4 qp = pb[q];
  float d10[10];
#pragma unroll
  for (int i = 0; i < 10; i++) d10[i] = 1e30f;
#pragma unroll 2
  for (int mm = 0; mm < 128; mm++) {
    int m = m0 + mm;
    float4 p = pb[m];                     // wave-uniform -> broadcast
    float dot = fmaf(qp.x, p.x, fmaf(qp.y, p.y, qp.z * p.z));
    float s = qp.w + p.w;
    float d = fmaf(-2.f, dot, s);
    d = (m == q) ? 1e30f : d;             // self-exclusion
    if (d < d10[9]) {
      float carry = d;
#pragma unroll
      for (int i = 0; i < 10; i++) {
        float lo = fminf(d10[i], carry);
        carry = fmaxf(d10[i], carry);
        d10[i] = lo;
      }
    }
  }
  int row = b * 4096 + q;
#pragma unroll
  for (int i = 0; i < 10; i++) candd[row * 80 + ch * 10 + i] = d10[i];
}

// Phase B: wave-per-query exact 10th-smallest of the 80 subset candidates.
__global__ void k_knn_merge(const float* __restrict__ candd, float* __restrict__ tq) {
  int gw = blockIdx.x * 4 + (threadIdx.x >> 6);   // 4096 blocks -> 16384 waves
  int l = threadIdx.x & 63;
  const float* cp = candd + (size_t)gw * 80;
  uint32_t k0 = fsort(cp[l]);
  uint32_t k1 = (l < 16) ? fsort(cp[64 + l]) : 0xFFFFFFFFu;
  uint32_t g = 0;
#pragma unroll
  for (int it = 0; it < 10; it++) {
    uint32_t m = k0 < k1 ? k0 : k1;
#pragma unroll
    for (int s = 1; s < 64; s <<= 1) {
      uint32_t o = __shfl_xor(m, s);
      m = o < m ? o : m;
    }
    g = m;
    if (it < 9) {
      if (k0 == m) k0 = 0xFFFFFFFFu;
      else if (k1 == m) k1 = 0xFFFFFFFFu;
    }
  }
  if (l == 0) tq[gw] = funsort(g);
}

// Phase C+D fused: LDS-staged chunked rescan, FOUR QUERIES PER THREAD so
// each ds_read_b128 is amortized over 4 cheap 3-fma filters (round-14
// lesson: the scan is LDS-instruction-bound at ~12cyc/read; r13 paid one
// read per (query,point) pair -> 20us floor; this cuts reads 4x).
// Block = (b, 32-query group); 512 blocks; thread = (quad ql4=t&7, sub=t>>3).
// 8 chunks x 512 points, stage stride 17 float4: 8 lanes/sub broadcast
// (free), 8 subs/wave in distinct bank groups => conflict-free (r10-verified).
// Filter margin 1e-3 >> chain discrepancy ~1e-5 => guaranteed superset;
// selection recomputes EXACT d (bit-identical fmaf chain vs k_knn_thr).
#define CFCAP 112
#define DMARGIN 1e-3f
__global__ __launch_bounds__(256) void k_knn_cf(
    const float4* __restrict__ pts4, const float* __restrict__ tq,
    int* __restrict__ idxout) {
  __shared__ float4 sp[544];                 // 32 subs x stride 17 (8.7 KB)
  __shared__ int candi[32 * CFCAP];          // 14 KB
  __shared__ int ccnt[32];
  int blk = blockIdx.x;           // 512 = b(4) x qg(128)
  int b = blk >> 7;
  int qg = blk & 127;
  int t = threadIdx.x;
  int ql4 = t & 7;                // query quad 0..7 -> queries ql4*4..+3
  int sub = t >> 3;               // 0..31 (16 points each per 512-chunk)
  if (t < 32) ccnt[t] = 0;
  const float4* pb = pts4 + b * 4096;
  int qbase = qg * 32 + ql4 * 4;
  float q2x[4], q2y[4], q2z[4], rhs[4];
#pragma unroll
  for (int j = 0; j < 4; j++) {
    float4 qp = pb[qbase + j];
    q2x[j] = -2.f * qp.x; q2y[j] = -2.f * qp.y; q2z[j] = -2.f * qp.z;
    rhs[j] = tq[b * 4096 + qbase + j] + DMARGIN - qp.w;
  }
  // padded stage slots for this thread's two points (p = t, p = 256+t)
  int s0 = (t >> 4) * 17 + (t & 15);
  int s1 = s0 + 272;
  for (int c = 0; c < 8; c++) {
    __syncthreads();              // prior chunk scan done (covers ccnt@c=0)
    sp[s0] = pb[c * 512 + t];
    sp[s1] = pb[c * 512 + 256 + t];
    __syncthreads();              // staging visible
    int base = sub * 17;
    int mb = c * 512 + sub * 16;
#pragma unroll
    for (int i = 0; i < 16; i++) {
      float4 p = sp[base + i];    // one read serves 4 queries
      int m = mb + i;
#pragma unroll
      for (int j = 0; j < 4; j++) {
        float tt = fmaf(q2x[j], p.x, fmaf(q2y[j], p.y, fmaf(q2z[j], p.z, p.w)));
        if (tt <= rhs[j]) {
          int qloc = ql4 * 4 + j;
          int pos = atomicAdd(&ccnt[qloc], 1);
          if (pos < CFCAP) candi[qloc * CFCAP + pos] = m;
        }
      }
    }
  }
  __syncthreads();
  // selection: 4 waves; wave w handles queries w*8 .. w*8+7.
  // Recompute EXACT d (bit-identical chain vs thr) for <=112 candidates.
  int w = t >> 6;
  int l = t & 63;
  for (int k = 0; k < 8; k++) {
    int qloc = w * 8 + k;
    int q2 = qg * 32 + qloc;
    float4 qp2 = pb[q2];
    int c = ccnt[qloc]; c = c < CFCAP ? c : CFCAP;
    unsigned long long k0 = ~0ULL, k1 = ~0ULL;
#pragma unroll
    for (int u = 0; u < 2; u++) {
      int j = u * 64 + l;
      if (j < c) {
        int m = candi[qloc * CFCAP + j];
        float4 p = pb[m];
        float dot = fmaf(qp2.x, p.x, fmaf(qp2.y, p.y, qp2.z * p.z));
        float s = qp2.w + p.w;
        float d = fmaf(-2.f, dot, s);        // EXACT, bit-identical to thr
        d = (m == q2) ? 1e30f : d;           // self-exclusion
        unsigned long long key = (((unsigned long long)fsort(d)) << 32) | (uint32_t)m;
        if (u == 0) k0 = key; else k1 = key;
      }
    }
    uint32_t keep[10];
#pragma unroll
    for (int it = 0; it < 10; it++) {
      unsigned long long m = k0 < k1 ? k0 : k1;
#pragma unroll
      for (int s = 1; s < 64; s <<= 1) {
        unsigned long long o = __shfl_xor(m, s);
        m = o < m ? o : m;
      }
      keep[it] = (uint32_t)(m & 0xffffffffu);
      if (k0 == m) k0 = ~0ULL;
      else if (k1 == m) k1 = ~0ULL;
    }
    if (l == 0) {
      int orow = b * 4096 + q2;
#pragma unroll
      for (int i = 0; i < 10; i++) idxout[orow * 10 + i] = (int)keep[i];
    }
  }
}

// ---------------- bf16 MFMA GEMM ----------------
// Y[p][o] = sum_k X[p][xoff+k] * W[o][k]   (X,W bf16; Y f32)
// BM=128, BN=64, BK=64. 256 threads = 4 waves (2x2). mfma 16x16x32.
__global__ __launch_bounds__(256) void k_gemm_bf(
    const uint16_t* __restrict__ Xb, int ldx, int xoff,
    const uint16_t* __restrict__ Wb, int ldw,
    float* __restrict__ Y, int ldy, int K) {
  __shared__ __align__(16) uint8_t lds[49152];
  const int t = threadIdx.x;
  const int l = t & 63;
  const int wid = t >> 6;
  const int wr = wid & 1, wc = wid >> 1;
  const int p0 = blockIdx.x * 128;
  const int o0 = blockIdx.y * 64;

  const int rA = l >> 3;                         // row within 8-row chunk
  const int cbp = ((l & 7) ^ rA) << 4;           // pre-swizzled byte col (staging)
  const int swl = (l & 7) << 4;                  // read-side swizzle XOR

  f32x4 acc[4][2];
#pragma unroll
  for (int mi = 0; mi < 4; mi++)
#pragma unroll
    for (int ni = 0; ni < 2; ni++) acc[mi][ni] = (f32x4)0.f;

  auto stage = [&](int k0, int buf) {
    const uint16_t* Xs_ = Xb + (size_t)p0 * ldx + xoff + k0;
    const uint16_t* Ws_ = Wb + (size_t)o0 * ldw + k0;
#pragma unroll
    for (int cc = 0; cc < 4; cc++) {
      int c = wid * 4 + cc;                      // A chunk 0..15 -> rows c*8..c*8+8
      const uint8_t* g = (const uint8_t*)(Xs_ + (size_t)(c * 8 + rA) * ldx) + cbp;
      async16(g, &lds[buf * 16384 + c * 1024]);
    }
#pragma unroll
    for (int cc = 0; cc < 2; cc++) {
      int c = wid * 2 + cc;                      // B chunk 0..7
      const uint8_t* g = (const uint8_t*)(Ws_ + (size_t)(c * 8 + rA) * ldw) + cbp;
      async16(g, &lds[32768 + buf * 8192 + c * 1024]);
    }
  };

  auto compute = [&](int buf) {
    const uint8_t* Ab = &lds[buf * 16384];
    const uint8_t* Bb = &lds[32768 + buf * 8192];
#pragma unroll
    for (int ks = 0; ks < 2; ks++) {
      int cb = ks * 64 + ((l >> 4) << 4);
      bf16x8 bfr[2];
#pragma unroll
      for (int ni = 0; ni < 2; ni++) {
        int n = wc * 32 + ni * 16 + (l & 15);
        bfr[ni] = *(const bf16x8*)(Bb + n * 128 + (cb ^ swl));
      }
#pragma unroll
      for (int mi = 0; mi < 4; mi++) {
        int m = wr * 64 + mi * 16 + (l & 15);
        bf16x8 afr = *(const bf16x8*)(Ab + m * 128 + (cb ^ swl));
        acc[mi][0] = __builtin_amdgcn_mfma_f32_16x16x32_bf16(afr, bfr[0], acc[mi][0], 0, 0, 0);
        acc[mi][1] = __builtin_amdgcn_mfma_f32_16x16x32_bf16(afr, bfr[1], acc[mi][1], 0, 0, 0);
      }
    }
  };

  const int nsteps = K >> 6;
  stage(0, 0);
  for (int s = 0; s < nsteps; s++) {
    __syncthreads();                              // drains in-flight loads
    if (s + 1 < nsteps) stage((s + 1) << 6, (s + 1) & 1);
    compute(s & 1);
  }

#pragma unroll
  for (int mi = 0; mi < 4; mi++)
#pragma unroll
    for (int ni = 0; ni < 2; ni++) {
      int col = o0 + wc * 32 + ni * 16 + (l & 15);
      int row0 = p0 + wr * 64 + mi * 16 + (l >> 4) * 4;
#pragma unroll
      for (int j = 0; j < 4; j++)
        Y[(size_t)(row0 + j) * ldy + col] = acc[mi][ni][j];
    }
}

// Gather pass (fp32 UV)
template <int O>
__global__ void k_gather(const float* __restrict__ UV, int ld, int voff,
                         const int* __restrict__ idx,
                         float* __restrict__ M,
                         float* __restrict__ T1, float* __restrict__ T2) {
  int L = blockIdx.x;             // 1024 blocks
  int rx = L & 7;
  int b = rx >> 1;
  int j = ((L >> 3) << 1) + (rx & 1);
  int n0 = j << 4;
  int o = threadIdx.x;
  float a1 = 0.f, a2 = 0.f;
  for (int pi = 0; pi < 16; pi++) {
    int row = b * 4096 + n0 + pi;
    float u = UV[row * ld + o];
    float s1 = 0.f, s2 = 0.f, vmax = -1e30f;
#pragma unroll
    for (int jj = 0; jj < KNN; jj++) {
      int m = idx[row * 10 + jj];
      float v = UV[(b * 4096 + m) * ld + voff + o];
      s1 += v;
      float x = u + v;
      s2 = fmaf(x, x, s2);
      vmax = fmaxf(vmax, v);
    }
    M[row * O + o] = vmax;
    a1 += 10.f * u + s1;
    a2 += s2;
  }
  atomicAdd(&T1[b * O + o], a1);
  atomicAdd(&T2[b * O + o], a2);
}

// x = lrelu((U + maxV - mu) * rsqrt(var+eps)) -> Xcat[:, coff:coff+O] (bf16)
template <int O>
__global__ void k_passB(const float* __restrict__ UV, int ld,
                        const float* __restrict__ M, int coff,
                        const float* __restrict__ T1, const float* __restrict__ T2,
                        uint16_t* __restrict__ Xcat) {
  int t = blockIdx.x * 256 + threadIdx.x;
  int o = t & (O - 1);
  int pn = t / O;
  int b = pn >> 12;
  float mu = T1[b * O + o] * (1.f / 40960.f);
  float e2 = T2[b * O + o] * (1.f / 40960.f);
  float inv = rsqrtf(e2 - mu * mu + 1e-5f);
  float x = (UV[pn * ld + o] + M[pn * O + o] - mu) * inv;
  Xcat[pn * 512 + coff + o] = f2bf(x >= 0.f ? x : 0.2f * x);
}

__global__ void k_stats3(const float* __restrict__ Y3, float* __restrict__ T1, float* __restrict__ T2) {
  int L = blockIdx.x;             // 1024
  int rx = L & 7;
  int b = rx >> 1;
  int j = ((L >> 3) << 1) + (rx & 1);
  int n0 = j << 4;
  int o = threadIdx.x;            // 128
  float a1 = 0.f, a2 = 0.f;
  for (int pi = 0; pi < 16; pi++) {
    float y = Y3[(b * 4096 + n0 + pi) * 128 + o];
    a1 += y;
    a2 = fmaf(y, y, a2);
  }
  atomicAdd(&T1[b * 128 + o], a1);
  atomicAdd(&T2[b * 128 + o], a2);
}

// out[b][o][n] = lrelu((Y3[b][n][o]-mu)*inv)  (transposing write)
__global__ void k_out(const float* __restrict__ Y3, const float* __restrict__ T1,
                      const float* __restrict__ T2, float* __restrict__ out) {
  __shared__ float tile[32][33];
  int bid = blockIdx.x;           // 2048
  int b = bid >> 9;
  int r = bid & 511;
  int n0 = (r >> 2) << 5;
  int o0 = (r & 3) << 5;
  int tx = threadIdx.x & 31, ty = threadIdx.x >> 5;
  int o = o0 + tx;
  float mu = T1[b * 128 + o] * (1.f / 4096.f);
  float e2 = T2[b * 128 + o] * (1.f / 4096.f);
  float inv = rsqrtf(e2 - mu * mu + 1e-5f);
#pragma unroll
  for (int i = 0; i < 4; i++) {
    int n = n0 + ty + i * 8;
    float v = (Y3[(b * 4096 + n) * 128 + o] - mu) * inv;
    tile[ty + i * 8][tx] = v >= 0.f ? v : 0.2f * v;
  }
  __syncthreads();
#pragma unroll
  for (int i = 0; i < 4; i++) {
    int oo = o0 + ty + i * 8;
    out[(b * 128 + oo) * 4096 + n0 + tx] = tile[tx][ty + i * 8];
  }
}

extern "C" void kernel_launch(void* const* d_in, const int* in_sizes, int n_in,
                              void* d_out, int out_size, void* d_ws, size_t ws_size,
                              hipStream_t stream) {
  const float* coords   = (const float*)d_in[0];
  const float* features = (const float*)d_in[1];
  const float* W1       = (const float*)d_in[2];
  const float* W2       = (const float*)d_in[3];
  const float* W3       = (const float*)d_in[4];
  float* out = (float*)d_out;

  float*    ws    = (float*)d_ws;
  uint16_t* Xcat  = (uint16_t*)ws;                 // bf16 [4][4096][512]
  float*    UV    = ws + 4194304;
  float*    Mbuf  = ws + 12582912;
  float*    Y3    = Mbuf;                          // alias (M dead by fuse GEMM)
  int*      idxb  = (int*)(ws + 16777216);
  uint16_t* W1cat = (uint16_t*)(ws + 16941056);
  uint16_t* W2cat = (uint16_t*)(ws + 16957440);
  uint16_t* W3b   = (uint16_t*)(ws + 16990208);
  float*    stats = ws + 17022976;
  // KNN scratch aliases UV region (all KNN kernels complete before stage-1 GEMM)
  float*  candd = UV;
  float*  tq    = UV + 1310720;
  float4* pts4  = (float4*)(UV + 1327104);

  k_prep<<<736, 256, 0, stream>>>(W1, W2, W3, coords, W1cat, W2cat, W3b, stats, pts4);
  k_trans_feat<<<2048, 256, 0, stream>>>(features, Xcat);
  k_knn_thr<<<512, 256, 0, stream>>>(pts4, candd);
  k_knn_merge<<<4096, 256, 0, stream>>>(candd, tq);
  k_knn_cf<<<512, 256, 0, stream>>>(pts4, tq, idxb);

  // stage 1: UV = Xcat[:, 0:128] @ W1cat^T  (O=256)
  k_gemm_bf<<<dim3(128, 4), 256, 0, stream>>>(Xcat, 512, 0, W1cat, 128, UV, 256, 128);
  k_gather<128><<<1024, 128, 0, stream>>>(UV, 256, 128, idxb, Mbuf, stats + 0, stats + 512);
  k_passB<128><<<8192, 256, 0, stream>>>(UV, 256, Mbuf, 128, stats + 0, stats + 512, Xcat);

  // stage 2: UV = Xcat[:, 128:256] @ W2cat^T (O=512)
  k_gemm_bf<<<dim3(128, 8), 256, 0, stream>>>(Xcat, 512, 128, W2cat, 128, UV, 512, 128);
  k_gather<256><<<1024, 256, 0, stream>>>(UV, 512, 256, idxb, Mbuf, stats + 1024, stats + 2048);
  k_passB<256><<<16384, 256, 0, stream>>>(UV, 512, Mbuf, 256, stats + 1024, stats + 2048, Xcat);

  // fuse: Y3 = Xcat[:, 0:512] @ W3b^T (O=128)
  k_gemm_bf<<<dim3(128, 2), 256, 0, stream>>>(Xcat, 512, 0, W3b, 512, Y3, 128, 512);
  k_stats3<<<1024, 128, 0, stream>>>(Y3, stats + 3072, stats + 3584);
  k_out<<<2048, 256, 0, stream>>>(Y3, stats + 3072, stats + 3584, out);
}

// Round 16
// 175.740 us; speedup vs baseline: 1.1996x; 1.1470x over previous
//
#include <hip/hip_runtime.h>
#include <math.h>
#include <stdint.h>

// Problem constants
#define NB 4
#define NC 128
#define NP 4096
#define KNN 10

// ---------------- ws layout (float-slot offsets) ----------------
// Xcat (bf16 u16) : [B][N][512]   @ 0         (4194304 float-slots = 16MB)
// UV   (f32)      : [B][N][512]   @ 4194304
// Mbuf (f32)      : [B][N][256]   @ 12582912  (Y3 aliases, [B][N][128])
// idx  (i32)      : [B][N][10]    @ 16777216
// W1cat (bf16)    : [256][128]    @ 16941056
// W2cat (bf16)    : [512][128]    @ 16957440
// W3b  (bf16)     : [128][512]    @ 16990208
// stats (f32)     : [8192]        @ 17022976
// KNN scratch aliases UV region (all KNN kernels run before stage-1 GEMM):
//   candd: [16384][80]    @ UV+0
//   tq   : [16384]        @ UV+1310720
//   pts4 : float4[16384]  @ UV+1327104  (x,y,z,|p|^2 — single source of truth)

__device__ __forceinline__ uint16_t f2bf(float f) {
  uint32_t u = __float_as_uint(f);
  u += 0x7fffu + ((u >> 16) & 1u);      // RNE
  return (uint16_t)(u >> 16);
}

__device__ __forceinline__ void async16(const void* g, void* l) {
  __builtin_amdgcn_global_load_lds(
      (const __attribute__((address_space(1))) unsigned int*)g,
      (__attribute__((address_space(3))) unsigned int*)l,
      16, 0, 0);
}

// float -> order-preserving uint32 (all finite values)
__device__ __forceinline__ uint32_t fsort(float f) {
  uint32_t u = __float_as_uint(f);
  return (u & 0x80000000u) ? ~u : (u | 0x80000000u);
}
__device__ __forceinline__ float funsort(uint32_t k) {
  uint32_t u = (k & 0x80000000u) ? (k & 0x7fffffffu) : ~k;
  return __uint_as_float(u);
}

typedef __bf16 bf16x8 __attribute__((ext_vector_type(8)));
typedef float f32x4 __attribute__((ext_vector_type(4)));

// prep: weight precompute + stats zero + pts4 pack (x,y,z,|p|^2)
__global__ void k_prep(const float* __restrict__ W1, const float* __restrict__ W2,
                       const float* __restrict__ W3, const float* __restrict__ coords,
                       uint16_t* __restrict__ W1cat, uint16_t* __restrict__ W2cat,
                       uint16_t* __restrict__ W3b,
                       float* __restrict__ stats, float4* __restrict__ pts4) {
  int t = blockIdx.x * 256 + threadIdx.x;
  if (t < 32768) {
    int o = t >> 7, c = t & 127;
    float v;
    if (o < 128) v = W1[o * 256 + c] - W1[o * 256 + 128 + c];     // A1 = W1a - W1b
    else         v = W1[(o - 128) * 256 + 128 + c];               // B1 = W1b
    W1cat[t] = f2bf(v);
  } else if (t < 98304) {
    int t2 = t - 32768;
    int o = t2 >> 7, c = t2 & 127;
    float v;
    if (o < 256) v = W2[o * 256 + c] - W2[o * 256 + 128 + c];     // A2
    else         v = W2[(o - 256) * 256 + 128 + c];               // B2
    W2cat[t2] = f2bf(v);
  } else if (t < 163840) {
    int t2 = t - 98304;
    W3b[t2] = f2bf(W3[t2]);
  } else if (t < 163840 + 8192) {
    stats[t - 163840] = 0.f;
  } else if (t < 163840 + 8192 + 16384) {
    int t2 = t - 163840 - 8192;
    int b = t2 >> 12, n = t2 & 4095;
    const float* cb = coords + b * 12288;
    float x = cb[n], y = cb[4096 + n], z = cb[8192 + n];
    float w = fmaf(x, x, fmaf(y, y, z * z));
    pts4[t2] = make_float4(x, y, z, w);
  }
}

// features [B][128][4096] (f32) -> Xcat[b][n][0:128] (bf16)
__global__ void k_trans_feat(const float* __restrict__ feat, uint16_t* __restrict__ Xcat) {
  __shared__ float tile[32][33];
  int bid = blockIdx.x;           // 2048
  int b = bid >> 9;
  int r = bid & 511;
  int n0 = (r >> 2) << 5;
  int c0 = (r & 3) << 5;
  int tx = threadIdx.x & 31, ty = threadIdx.x >> 5;   // 256 threads
#pragma unroll
  for (int i = 0; i < 4; i++) {
    int c = c0 + ty + i * 8;
    tile[ty + i * 8][tx] = feat[(b * 128 + c) * 4096 + n0 + tx];
  }
  __syncthreads();
#pragma unroll
  for (int i = 0; i < 4; i++) {
    int n = n0 + ty + i * 8;
    Xcat[((b * 4096 + n) * 512) + c0 + tx] = f2bf(tile[tx][ty + i * 8]);
  }
}

// ---------------- KNN: exact subsampled-threshold scheme ----------------
// d = (q.w + p.w) - 2 q.p with explicit fmaf, operands from pts4 everywhere:
// thr and the cf exact-recompute are bit-identical by construction.
// Phase A: per-chunk sorted top-10 over SUBSET = first 1024 points.
__global__ void k_knn_thr(const float4* __restrict__ pts4, float* __restrict__ candd) {
  int L = blockIdx.x;             // 512 = b(4) x qb(16) x ch(8)
  int ch = L & 7;
  int qb = (L >> 3) & 15;
  int b = L >> 7;
  int m0 = ch << 7;               // subset points ch*128 .. +127  (all < 1024)
  const float4* pb = pts4 + b * 4096;
  int t = threadIdx.x;
  int q = (qb << 8) + t;
  float4 qp = pb[q];
  float d10[10];
#pragma unroll
  for (int i = 0; i < 10; i++) d10[i] = 1e30f;
#pragma unroll 2
  for (int mm = 0; mm < 128; mm++) {
    int m = m0 + mm;
    float4 p = pb[m];                     // wave-uniform -> broadcast
    float dot = fmaf(qp.x, p.x, fmaf(qp.y, p.y, qp.z * p.z));
    float s = qp.w + p.w;
    float d = fmaf(-2.f, dot, s);
    d = (m == q) ? 1e30f : d;             // self-exclusion
    if (d < d10[9]) {
      float carry = d;
#pragma unroll
      for (int i = 0; i < 10; i++) {
        float lo = fminf(d10[i], carry);
        carry = fmaxf(d10[i], carry);
        d10[i] = lo;
      }
    }
  }
  int row = b * 4096 + q;
#pragma unroll
  for (int i = 0; i < 10; i++) candd[row * 80 + ch * 10 + i] = d10[i];
}

// Phase B: wave-per-query exact 10th-smallest of the 80 subset candidates.
__global__ void k_knn_merge(const float* __restrict__ candd, float* __restrict__ tq) {
  int gw = blockIdx.x * 4 + (threadIdx.x >> 6);   // 4096 blocks -> 16384 waves
  int l = threadIdx.x & 63;
  const float* cp = candd + (size_t)gw * 80;
  uint32_t k0 = fsort(cp[l]);
  uint32_t k1 = (l < 16) ? fsort(cp[64 + l]) : 0xFFFFFFFFu;
  uint32_t g = 0;
#pragma unroll
  for (int it = 0; it < 10; it++) {
    uint32_t m = k0 < k1 ? k0 : k1;
#pragma unroll
    for (int s = 1; s < 64; s <<= 1) {
      uint32_t o = __shfl_xor(m, s);
      m = o < m ? o : m;
    }
    g = m;
    if (it < 9) {
      if (k0 == m) k0 = 0xFFFFFFFFu;
      else if (k1 == m) k1 = 0xFFFFFFFFu;
    }
  }
  if (l == 0) tq[gw] = funsort(g);
}

// Phase C+D fused: REGISTER-QUERY / PARTITIONED-POINT scan. Block = (b,
// 8-query group), 2048 blocks. All 8 queries live in EVERY thread's
// registers; threads partition the 4096 points (16 coalesced global
// float4 loads each, pts4 is L2-resident 64 KB/batch). Each point is
// consumed by exactly ONE thread -> no LDS point staging, no scan
// barriers (r8-r15 lesson: the staging+barrier structure was the tax).
// Cheap 3-fma filter, margin 1e-3 >> chain discrepancy ~1e-5 =>
// guaranteed superset; hits (~1% of pairs) pushed to LDS candidate
// lists. Selection recomputes EXACT d (bit-identical fmaf chain vs
// k_knn_thr; self excluded there) + wave-parallel (d,idx) top-10.
#define CFCAP 112
#define DMARGIN 1e-3f
__global__ __launch_bounds__(256) void k_knn_cf(
    const float4* __restrict__ pts4, const float* __restrict__ tq,
    int* __restrict__ idxout) {
  __shared__ int candi[8 * CFCAP];           // 3.5 KB
  __shared__ int ccnt[8];
  int blk = blockIdx.x;           // 2048 = b(4) x qg(512)
  int b = blk >> 9;
  int qg = blk & 511;
  int t = threadIdx.x;
  if (t < 8) ccnt[t] = 0;
  const float4* pb = pts4 + b * 4096;
  int qbase = qg * 8;
  float q2x[8], q2y[8], q2z[8], rhs[8];
#pragma unroll
  for (int j = 0; j < 8; j++) {
    float4 qp = pb[qbase + j];
    q2x[j] = -2.f * qp.x; q2y[j] = -2.f * qp.y; q2z[j] = -2.f * qp.z;
    rhs[j] = tq[b * 4096 + qbase + j] + DMARGIN - qp.w;
  }
  __syncthreads();                // ccnt init visible
#pragma unroll 4
  for (int c = 0; c < 16; c++) {
    float4 p = pb[c * 256 + t];   // coalesced global (L2-resident)
    int m = c * 256 + t;
#pragma unroll
    for (int j = 0; j < 8; j++) {
      float tt = fmaf(q2x[j], p.x, fmaf(q2y[j], p.y, fmaf(q2z[j], p.z, p.w)));
      if (tt <= rhs[j]) {
        int pos = atomicAdd(&ccnt[j], 1);
        if (pos < CFCAP) candi[j * CFCAP + pos] = m;
      }
    }
  }
  __syncthreads();
  // selection: 4 waves; wave w handles queries w*2, w*2+1.
  // Recompute EXACT d (bit-identical chain vs thr) for <=112 candidates.
  int w = t >> 6;
  int l = t & 63;
  for (int k = 0; k < 2; k++) {
    int qloc = w * 2 + k;
    int q2 = qbase + qloc;
    float4 qp2 = pb[q2];
    int c = ccnt[qloc]; c = c < CFCAP ? c : CFCAP;
    unsigned long long k0 = ~0ULL, k1 = ~0ULL;
#pragma unroll
    for (int u = 0; u < 2; u++) {
      int j = u * 64 + l;
      if (j < c) {
        int m = candi[qloc * CFCAP + j];
        float4 p = pb[m];
        float dot = fmaf(qp2.x, p.x, fmaf(qp2.y, p.y, qp2.z * p.z));
        float s = qp2.w + p.w;
        float d = fmaf(-2.f, dot, s);        // EXACT, bit-identical to thr
        d = (m == q2) ? 1e30f : d;           // self-exclusion
        unsigned long long key = (((unsigned long long)fsort(d)) << 32) | (uint32_t)m;
        if (u == 0) k0 = key; else k1 = key;
      }
    }
    uint32_t keep[10];
#pragma unroll
    for (int it = 0; it < 10; it++) {
      unsigned long long m = k0 < k1 ? k0 : k1;
#pragma unroll
      for (int s = 1; s < 64; s <<= 1) {
        unsigned long long o = __shfl_xor(m, s);
        m = o < m ? o : m;
      }
      keep[it] = (uint32_t)(m & 0xffffffffu);
      if (k0 == m) k0 = ~0ULL;
      else if (k1 == m) k1 = ~0ULL;
    }
    if (l == 0) {
      int orow = b * 4096 + q2;
#pragma unroll
      for (int i = 0; i < 10; i++) idxout[orow * 10 + i] = (int)keep[i];
    }
  }
}

// ---------------- bf16 MFMA GEMM ----------------
// Y[p][o] = sum_k X[p][xoff+k] * W[o][k]   (X,W bf16; Y f32)
// BM=128, BN=64, BK=64. 256 threads = 4 waves (2x2). mfma 16x16x32.
__global__ __launch_bounds__(256) void k_gemm_bf(
    const uint16_t* __restrict__ Xb, int ldx, int xoff,
    const uint16_t* __restrict__ Wb, int ldw,
    float* __restrict__ Y, int ldy, int K) {
  __shared__ __align__(16) uint8_t lds[49152];
  const int t = threadIdx.x;
  const int l = t & 63;
  const int wid = t >> 6;
  const int wr = wid & 1, wc = wid >> 1;
  const int p0 = blockIdx.x * 128;
  const int o0 = blockIdx.y * 64;

  const int rA = l >> 3;                         // row within 8-row chunk
  const int cbp = ((l & 7) ^ rA) << 4;           // pre-swizzled byte col (staging)
  const int swl = (l & 7) << 4;                  // read-side swizzle XOR

  f32x4 acc[4][2];
#pragma unroll
  for (int mi = 0; mi < 4; mi++)
#pragma unroll
    for (int ni = 0; ni < 2; ni++) acc[mi][ni] = (f32x4)0.f;

  auto stage = [&](int k0, int buf) {
    const uint16_t* Xs_ = Xb + (size_t)p0 * ldx + xoff + k0;
    const uint16_t* Ws_ = Wb + (size_t)o0 * ldw + k0;
#pragma unroll
    for (int cc = 0; cc < 4; cc++) {
      int c = wid * 4 + cc;                      // A chunk 0..15 -> rows c*8..c*8+8
      const uint8_t* g = (const uint8_t*)(Xs_ + (size_t)(c * 8 + rA) * ldx) + cbp;
      async16(g, &lds[buf * 16384 + c * 1024]);
    }
#pragma unroll
    for (int cc = 0; cc < 2; cc++) {
      int c = wid * 2 + cc;                      // B chunk 0..7
      const uint8_t* g = (const uint8_t*)(Ws_ + (size_t)(c * 8 + rA) * ldw) + cbp;
      async16(g, &lds[32768 + buf * 8192 + c * 1024]);
    }
  };

  auto compute = [&](int buf) {
    const uint8_t* Ab = &lds[buf * 16384];
    const uint8_t* Bb = &lds[32768 + buf * 8192];
#pragma unroll
    for (int ks = 0; ks < 2; ks++) {
      int cb = ks * 64 + ((l >> 4) << 4);
      bf16x8 bfr[2];
#pragma unroll
      for (int ni = 0; ni < 2; ni++) {
        int n = wc * 32 + ni * 16 + (l & 15);
        bfr[ni] = *(const bf16x8*)(Bb + n * 128 + (cb ^ swl));
      }
#pragma unroll
      for (int mi = 0; mi < 4; mi++) {
        int m = wr * 64 + mi * 16 + (l & 15);
        bf16x8 afr = *(const bf16x8*)(Ab + m * 128 + (cb ^ swl));
        acc[mi][0] = __builtin_amdgcn_mfma_f32_16x16x32_bf16(afr, bfr[0], acc[mi][0], 0, 0, 0);
        acc[mi][1] = __builtin_amdgcn_mfma_f32_16x16x32_bf16(afr, bfr[1], acc[mi][1], 0, 0, 0);
      }
    }
  };

  const int nsteps = K >> 6;
  stage(0, 0);
  for (int s = 0; s < nsteps; s++) {
    __syncthreads();                              // drains in-flight loads
    if (s + 1 < nsteps) stage((s + 1) << 6, (s + 1) & 1);
    compute(s & 1);
  }

#pragma unroll
  for (int mi = 0; mi < 4; mi++)
#pragma unroll
    for (int ni = 0; ni < 2; ni++) {
      int col = o0 + wc * 32 + ni * 16 + (l & 15);
      int row0 = p0 + wr * 64 + mi * 16 + (l >> 4) * 4;
#pragma unroll
      for (int j = 0; j < 4; j++)
        Y[(size_t)(row0 + j) * ldy + col] = acc[mi][ni][j];
    }
}

// Gather pass (fp32 UV)
template <int O>
__global__ void k_gather(const float* __restrict__ UV, int ld, int voff,
                         const int* __restrict__ idx,
                         float* __restrict__ M,
                         float* __restrict__ T1, float* __restrict__ T2) {
  int L = blockIdx.x;             // 1024 blocks
  int rx = L & 7;
  int b = rx >> 1;
  int j = ((L >> 3) << 1) + (rx & 1);
  int n0 = j << 4;
  int o = threadIdx.x;
  float a1 = 0.f, a2 = 0.f;
  for (int pi = 0; pi < 16; pi++) {
    int row = b * 4096 + n0 + pi;
    float u = UV[row * ld + o];
    float s1 = 0.f, s2 = 0.f, vmax = -1e30f;
#pragma unroll
    for (int jj = 0; jj < KNN; jj++) {
      int m = idx[row * 10 + jj];
      float v = UV[(b * 4096 + m) * ld + voff + o];
      s1 += v;
      float x = u + v;
      s2 = fmaf(x, x, s2);
      vmax = fmaxf(vmax, v);
    }
    M[row * O + o] = vmax;
    a1 += 10.f * u + s1;
    a2 += s2;
  }
  atomicAdd(&T1[b * O + o], a1);
  atomicAdd(&T2[b * O + o], a2);
}

// x = lrelu((U + maxV - mu) * rsqrt(var+eps)) -> Xcat[:, coff:coff+O] (bf16)
template <int O>
__global__ void k_passB(const float* __restrict__ UV, int ld,
                        const float* __restrict__ M, int coff,
                        const float* __restrict__ T1, const float* __restrict__ T2,
                        uint16_t* __restrict__ Xcat) {
  int t = blockIdx.x * 256 + threadIdx.x;
  int o = t & (O - 1);
  int pn = t / O;
  int b = pn >> 12;
  float mu = T1[b * O + o] * (1.f / 40960.f);
  float e2 = T2[b * O + o] * (1.f / 40960.f);
  float inv = rsqrtf(e2 - mu * mu + 1e-5f);
  float x = (UV[pn * ld + o] + M[pn * O + o] - mu) * inv;
  Xcat[pn * 512 + coff + o] = f2bf(x >= 0.f ? x : 0.2f * x);
}

__global__ void k_stats3(const float* __restrict__ Y3, float* __restrict__ T1, float* __restrict__ T2) {
  int L = blockIdx.x;             // 1024
  int rx = L & 7;
  int b = rx >> 1;
  int j = ((L >> 3) << 1) + (rx & 1);
  int n0 = j << 4;
  int o = threadIdx.x;            // 128
  float a1 = 0.f, a2 = 0.f;
  for (int pi = 0; pi < 16; pi++) {
    float y = Y3[(b * 4096 + n0 + pi) * 128 + o];
    a1 += y;
    a2 = fmaf(y, y, a2);
  }
  atomicAdd(&T1[b * 128 + o], a1);
  atomicAdd(&T2[b * 128 + o], a2);
}

// out[b][o][n] = lrelu((Y3[b][n][o]-mu)*inv)  (transposing write)
__global__ void k_out(const float* __restrict__ Y3, const float* __restrict__ T1,
                      const float* __restrict__ T2, float* __restrict__ out) {
  __shared__ float tile[32][33];
  int bid = blockIdx.x;           // 2048
  int b = bid >> 9;
  int r = bid & 511;
  int n0 = (r >> 2) << 5;
  int o0 = (r & 3) << 5;
  int tx = threadIdx.x & 31, ty = threadIdx.x >> 5;
  int o = o0 + tx;
  float mu = T1[b * 128 + o] * (1.f / 4096.f);
  float e2 = T2[b * 128 + o] * (1.f / 4096.f);
  float inv = rsqrtf(e2 - mu * mu + 1e-5f);
#pragma unroll
  for (int i = 0; i < 4; i++) {
    int n = n0 + ty + i * 8;
    float v = (Y3[(b * 4096 + n) * 128 + o] - mu) * inv;
    tile[ty + i * 8][tx] = v >= 0.f ? v : 0.2f * v;
  }
  __syncthreads();
#pragma unroll
  for (int i = 0; i < 4; i++) {
    int oo = o0 + ty + i * 8;
    out[(b * 128 + oo) * 4096 + n0 + tx] = tile[tx][ty + i * 8];
  }
}

extern "C" void kernel_launch(void* const* d_in, const int* in_sizes, int n_in,
                              void* d_out, int out_size, void* d_ws, size_t ws_size,
                              hipStream_t stream) {
  const float* coords   = (const float*)d_in[0];
  const float* features = (const float*)d_in[1];
  const float* W1       = (const float*)d_in[2];
  const float* W2       = (const float*)d_in[3];
  const float* W3       = (const float*)d_in[4];
  float* out = (float*)d_out;

  float*    ws    = (float*)d_ws;
  uint16_t* Xcat  = (uint16_t*)ws;                 // bf16 [4][4096][512]
  float*    UV    = ws + 4194304;
  float*    Mbuf  = ws + 12582912;
  float*    Y3    = Mbuf;                          // alias (M dead by fuse GEMM)
  int*      idxb  = (int*)(ws + 16777216);
  uint16_t* W1cat = (uint16_t*)(ws + 16941056);
  uint16_t* W2cat = (uint16_t*)(ws + 16957440);
  uint16_t* W3b   = (uint16_t*)(ws + 16990208);
  float*    stats = ws + 17022976;
  // KNN scratch aliases UV region (all KNN kernels complete before stage-1 GEMM)
  float*  candd = UV;
  float*  tq    = UV + 1310720;
  float4* pts4  = (float4*)(UV + 1327104);

  k_prep<<<736, 256, 0, stream>>>(W1, W2, W3, coords, W1cat, W2cat, W3b, stats, pts4);
  k_trans_feat<<<2048, 256, 0, stream>>>(features, Xcat);
  k_knn_thr<<<512, 256, 0, stream>>>(pts4, candd);
  k_knn_merge<<<4096, 256, 0, stream>>>(candd, tq);
  k_knn_cf<<<2048, 256, 0, stream>>>(pts4, tq, idxb);

  // stage 1: UV = Xcat[:, 0:128] @ W1cat^T  (O=256)
  k_gemm_bf<<<dim3(128, 4), 256, 0, stream>>>(Xcat, 512, 0, W1cat, 128, UV, 256, 128);
  k_gather<128><<<1024, 128, 0, stream>>>(UV, 256, 128, idxb, Mbuf, stats + 0, stats + 512);
  k_passB<128><<<8192, 256, 0, stream>>>(UV, 256, Mbuf, 128, stats + 0, stats + 512, Xcat);

  // stage 2: UV = Xcat[:, 128:256] @ W2cat^T (O=512)
  k_gemm_bf<<<dim3(128, 8), 256, 0, stream>>>(Xcat, 512, 128, W2cat, 128, UV, 512, 128);
  k_gather<256><<<1024, 256, 0, stream>>>(UV, 512, 256, idxb, Mbuf, stats + 1024, stats + 2048);
  k_passB<256><<<16384, 256, 0, stream>>>(UV, 512, Mbuf, 256, stats + 1024, stats + 2048, Xcat);

  // fuse: Y3 = Xcat[:, 0:512] @ W3b^T (O=128)
  k_gemm_bf<<<dim3(128, 2), 256, 0, stream>>>(Xcat, 512, 0, W3b, 512, Y3, 128, 512);
  k_stats3<<<1024, 128, 0, stream>>>(Y3, stats + 3072, stats + 3584);
  k_out<<<2048, 256, 0, stream>>>(Y3, stats + 3072, stats + 3584, out);
}